// Round 1
// baseline (11.740 us; speedup 1.0000x reference)
//
#include <hip/hip_runtime.h>
#include <hip/hip_bf16.h>

// out[b, c, r] = x[b, c, i, j], i = v[b, r, 0], j = v[b, r, 1]
// x: (B=16, C=256, H4=128, W4=128) f32
// v: (B=16, N_RAY=90, 2) int (harness delivers integer inputs as int32)
// out: (B, C, N_RAY) f32
//
// Thread mapping: linear idx over (b, c, r) with r fastest -> coalesced
// 90-wide output writes per (b, c) row. Vertex reads are broadcast-shared
// across the 256 c-values (L1/L2 hit). x reads are gathers (latency-bound).

#define B_    16
#define C_    256
#define H4_   128
#define W4_   128
#define NRAY_ 90
#define TOTAL_ (B_ * C_ * NRAY_)

__global__ __launch_bounds__(256) void vertex_sampler_kernel(
    const float* __restrict__ x,
    const int* __restrict__ v,
    float* __restrict__ out)
{
    int idx = blockIdx.x * blockDim.x + threadIdx.x;
    if (idx >= TOTAL_) return;

    int r  = idx % NRAY_;
    int bc = idx / NRAY_;   // b * C + c
    int b  = bc / C_;

    int i = v[(b * NRAY_ + r) * 2 + 0];
    int j = v[(b * NRAY_ + r) * 2 + 1];

    out[idx] = x[(size_t)bc * (H4_ * W4_) + i * W4_ + j];
}

extern "C" void kernel_launch(void* const* d_in, const int* in_sizes, int n_in,
                              void* d_out, int out_size, void* d_ws, size_t ws_size,
                              hipStream_t stream) {
    const float* x = (const float*)d_in[0];
    const int*   v = (const int*)d_in[1];
    float*     out = (float*)d_out;

    const int block = 256;
    const int grid  = (TOTAL_ + block - 1) / block;  // 1440 blocks
    vertex_sampler_kernel<<<grid, block, 0, stream>>>(x, v, out);
}

// Round 2
// 11.625 us; speedup vs baseline: 1.0099x; 1.0099x over previous
//
#include <hip/hip_runtime.h>
#include <hip/hip_bf16.h>

// out[b, c, r] = x[b, c, i, j], i = v[b, r, 0], j = v[b, r, 1]
// x: (B=16, C=256, H4=128, W4=128) f32
// v: (B=16, N_RAY=90, 2) int32 -> viewed as (B, 45, int4) = (i0,j0,i1,j1)
// out: (B, C, N_RAY=90) f32 -> viewed as (B, C, 45) float2
//
// Ray-pairing: each thread handles 2 consecutive rays for one (b,c):
//   - one int4 vertex load (16B aligned: byte off = 2880*b + 16*t)
//   - two independent scalar gathers from x (random lines, irreducible)
//   - one float2 output store (8B aligned: row off = 360*bc + 8*t)
// Halves wave count vs scalar version (2880 vs 5760 waves), quarters
// vertex-load instrs, halves stores. Gather count unchanged (it's the
// inherent cost: 368,640 random 64B lines, L3-resident on replay).

#define B_    16
#define C_    256
#define H4_   128
#define W4_   128
#define NPAIR_ 45                       // N_RAY / 2
#define TOTAL_ (B_ * C_ * NPAIR_)       // 184,320 threads

__global__ __launch_bounds__(256) void vertex_sampler_kernel(
    const float* __restrict__ x,
    const int4* __restrict__ v,         // (B, 45) int4
    float2* __restrict__ out)           // (B, C, 45) float2
{
    int idx = blockIdx.x * blockDim.x + threadIdx.x;
    if (idx >= TOTAL_) return;

    int t  = idx % NPAIR_;
    int bc = idx / NPAIR_;   // b * C + c
    int b  = bc >> 8;        // C = 256

    int4 vv = v[b * NPAIR_ + t];   // (i0, j0, i1, j1)

    const float* xb = x + (size_t)bc * (H4_ * W4_);
    float2 o;
    o.x = xb[vv.x * W4_ + vv.y];
    o.y = xb[vv.z * W4_ + vv.w];

    out[idx] = o;            // out index == idx (b,c,t layout matches)
}

extern "C" void kernel_launch(void* const* d_in, const int* in_sizes, int n_in,
                              void* d_out, int out_size, void* d_ws, size_t ws_size,
                              hipStream_t stream) {
    const float* x = (const float*)d_in[0];
    const int4*  v = (const int4*)d_in[1];
    float2*    out = (float2*)d_out;

    const int block = 256;
    const int grid  = (TOTAL_ + block - 1) / block;  // 720 blocks
    vertex_sampler_kernel<<<grid, block, 0, stream>>>(x, v, out);
}